// Round 3
// baseline (240.573 us; speedup 1.0000x reference)
//
#include <hip/hip_runtime.h>

// out[b,s] = cumsum_s( softplus(beta * c[b,s]) / beta ), fp32, B=4096, S=8192.
//
// R4 design: BARRIER-FREE. One wave per row, shuffle-only scan.
//   Post-mortem R3: hipcc drains vmcnt(0)+lgkmcnt(0) before every s_barrier,
//   so "prefetch across __syncthreads" is impossible; the per-row barrier
//   kept all resident waves convoy-phased (burst load / silent compute /
//   burst store) -> HBM duty ~30%, dur 86us with every pipe <35% busy.
//   Fix: remove ALL cross-wave coordination.
//   - 4096 rows -> 4096 waves (1024 blocks x 256 thr). 16 waves/CU resident,
//     free-running, never synchronized -> load/store phases decorrelate and
//     the memory system sees a continuous stream (fillBuffer in the same
//     trace hits 6.7 TB/s barrier-free).
//   - Row = 8 passes of 1024 elems. Per pass, lane holds 4 float4 chunks at
//     chunk index c = j*64+lane (perfectly coalesced 1KB/instr loads+stores).
//     Scan = in-chunk (registers) + 4 INDEPENDENT 6-step wave shuffle scans
//     + scalar carry across passes (the only serial dependence, 4 adds).
//   - 2-deep software pipeline: loads for pass p+2 issued while computing
//     pass p; no barrier ever drains them (8KB in flight per wave).
//   - Plain stores (R3 measured: nontemporal stores INCREASED WRITE_SIZE
//     131->145 GB and FETCH; reverted).
//   - No LDS at all.

#define ROW_S   8192
#define NJ      4                        // float4 chunks per lane per pass
#define PASS_F4 (64 * NJ)                // 256 float4 = 1024 elems per pass
#define NPASS   (ROW_S / (PASS_F4 * 4))  // 8 passes per row
#define WPB     4                        // waves per block
#define BLOCK_T (WPB * 64)

typedef float f32x4 __attribute__((ext_vector_type(4)));

__device__ __forceinline__ float softplus_step(float c, float beta, float inv_beta) {
    float tb = beta * c;
    float a  = fabsf(tb);
    float e  = __expf(-a);             // in (0,1], no overflow
    float l  = __logf(1.0f + e);       // log1p(exp(-|t|))
    return (fmaxf(tb, 0.0f) + l) * inv_beta;
}

__global__ __launch_bounds__(BLOCK_T, 4) void softplus_cumsum_kernel(
    const float* __restrict__ c,
    const float* __restrict__ beta_p,
    float* __restrict__ out,
    int nrows)
{
    const int lane = threadIdx.x & 63;
    const int wave = threadIdx.x >> 6;
    const int row  = blockIdx.x * WPB + wave;
    if (row >= nrows) return;                       // wave-uniform exit

    const float beta     = beta_p[0];
    const float inv_beta = 1.0f / beta;

    const f32x4* __restrict__ in4  = (const f32x4*)c   + (size_t)row * (ROW_S / 4);
    f32x4*       __restrict__ out4 = (f32x4*)out       + (size_t)row * (ROW_S / 4);

    float carry = 0.0f;

    // ---- 2-deep pipeline prologue: passes 0 and 1 in flight ----
    f32x4 va[NJ], vb[NJ];
    #pragma unroll
    for (int j = 0; j < NJ; ++j) va[j] = in4[0 * PASS_F4 + j * 64 + lane];
    #pragma unroll
    for (int j = 0; j < NJ; ++j) vb[j] = in4[1 * PASS_F4 + j * 64 + lane];

    // body(cur, nxt, p): consume cur (pass p), refill cur with pass p+2.
    auto body = [&](f32x4 (&cur)[NJ], const int p) {
        // softplus + in-chunk inclusive scan (consumes cur)
        f32x4 r[NJ];
        float s[NJ];
        #pragma unroll
        for (int j = 0; j < NJ; ++j) {
            float a = softplus_step(cur[j].x, beta, inv_beta);
            float b = softplus_step(cur[j].y, beta, inv_beta);
            float d = softplus_step(cur[j].z, beta, inv_beta);
            float e = softplus_step(cur[j].w, beta, inv_beta);
            r[j].x = a;
            r[j].y = a + b;
            r[j].z = r[j].y + d;
            r[j].w = r[j].z + e;
            s[j]   = r[j].w;
        }

        // refill: issue loads for pass p+2 into the freed buffer.
        // Consumed 2 bodies later -> stays in flight across ~2 full passes.
        if (p + 2 < NPASS) {
            #pragma unroll
            for (int j = 0; j < NJ; ++j)
                cur[j] = in4[(p + 2) * PASS_F4 + j * 64 + lane];
        }

        // 4 independent wave-inclusive shuffle scans of the chunk sums
        float xs[NJ], G[NJ];
        #pragma unroll
        for (int j = 0; j < NJ; ++j) {
            float x = s[j];
            #pragma unroll
            for (int d = 1; d < 64; d <<= 1) {
                float y = __shfl_up(x, d, 64);
                if (lane >= d) x += y;
            }
            xs[j] = x;                       // inclusive over lanes
            G[j]  = __shfl(x, 63, 64);       // pass-group total, broadcast
        }

        // combine + coalesced stores (plain, not nt)
        float pre = carry;
        #pragma unroll
        for (int j = 0; j < NJ; ++j) {
            const float off = pre + (xs[j] - s[j]);   // exclusive lane prefix
            pre += G[j];
            f32x4 o;
            o.x = r[j].x + off;
            o.y = r[j].y + off;
            o.z = r[j].z + off;
            o.w = r[j].w + off;
            out4[p * PASS_F4 + j * 64 + lane] = o;
        }
        carry = pre;
    };

    // NPASS = 8, fully static ping-pong (no runtime-indexed buffers -> no scratch)
    body(va, 0); body(vb, 1);
    body(va, 2); body(vb, 3);
    body(va, 4); body(vb, 5);
    body(va, 6); body(vb, 7);
}

extern "C" void kernel_launch(void* const* d_in, const int* in_sizes, int n_in,
                              void* d_out, int out_size, void* d_ws, size_t ws_size,
                              hipStream_t stream) {
    const float* c      = (const float*)d_in[0];
    const float* beta_p = (const float*)d_in[1];
    float*       out    = (float*)d_out;

    const int B    = in_sizes[0] / ROW_S;            // 4096 rows
    const int grid = (B + WPB - 1) / WPB;            // 1024 blocks

    softplus_cumsum_kernel<<<dim3(grid), dim3(BLOCK_T), 0, stream>>>(
        c, beta_p, out, B);
}